// Round 4
// baseline (8176.300 us; speedup 1.0000x reference)
//
#include <hip/hip_runtime.h>
#include <hip/hip_fp16.h>
#include <stdint.h>

#define Kn 64
#define En 256
#define Bn 512
#define Hn 512
#define Dn 128
#define NB 256       // blocks (2 samples each)
#define NT 1024      // 16 waves
#define DT_C 0.05f

// ws layout (bytes):
//   [0, 131072)      pos (int, Kn*Bn): pos[k*Bn+b] = e or -1
//   [131072, 131080) acc (float x2): loss, tot_m
//   [131088, 131344) ctr (int x64): per-event soft-barrier counters
//   [131584, ...)    f16 weights (__half), 16B-aligned
// half-unit offsets: W1 0, W2 262144, Wp1 524288, Wp2 786432, Wg 851968
//   Wg = 4 gate matrices interleaved: [640 rows][2048 = g*512 + j]

__device__ __forceinline__ float sigm(float x){ return 1.0f/(1.0f + __expf(-x)); }

__global__ void k_init(int* __restrict__ pos, float* __restrict__ acc, int* __restrict__ ctr){
  int i = blockIdx.x*blockDim.x + threadIdx.x;
  if (i < Kn*Bn) pos[i] = -1;
  if (i < 2) acc[i] = 0.0f;
  if (i < Kn) ctr[i] = 0;
}

__global__ void k_scatter(const int* __restrict__ bidx, int* __restrict__ pos){
  int i = blockIdx.x*blockDim.x + threadIdx.x;
  if (i < Kn*En){
    int k = i >> 8;
    int e = i & (En-1);
    pos[(k << 9) | bidx[i]] = e;
  }
}

__global__ void k_cvt(const float* __restrict__ src, __half* __restrict__ dst, int n){
  int i = blockIdx.x*blockDim.x + threadIdx.x;
  if (i < n) dst[i] = __float2half(src[i]);
}

__global__ void k_cvt_g(const float* __restrict__ src, __half* __restrict__ dst, int g){
  int i = blockIdx.x*blockDim.x + threadIdx.x;
  if (i < 640*512){
    int r = i >> 9, j = i & 511;
    dst[(size_t)r*2048 + g*512 + j] = __float2half(src[i]);
  }
}

// bounded-spin phase-lock barrier: perf device only, never a correctness dep
__device__ __forceinline__ void soft_sync(int* ctr, int target){
  __syncthreads();
  if (threadIdx.x == 0){
    __hip_atomic_fetch_add(ctr, 1, __ATOMIC_RELEASE, __HIP_MEMORY_SCOPE_AGENT);
    for (int sp=0; sp<8192; ++sp){
      if (__hip_atomic_load(ctr, __ATOMIC_ACQUIRE, __HIP_MEMORY_SCOPE_AGENT) >= target) break;
      __builtin_amdgcn_s_sleep(2);
    }
  }
  __syncthreads();
}

// 8 fp32 FMAs from one uint4 (8 f16 weights); compiler emits v_fma_mix_f32
#define FMA8(HV, U) do{                                                \
  const __half2* _hp = reinterpret_cast<const __half2*>(&(U));         \
  a[0]=fmaf((HV), __low2float (_hp[0]), a[0]);                         \
  a[1]=fmaf((HV), __high2float(_hp[0]), a[1]);                         \
  a[2]=fmaf((HV), __low2float (_hp[1]), a[2]);                         \
  a[3]=fmaf((HV), __high2float(_hp[1]), a[3]);                         \
  a[4]=fmaf((HV), __low2float (_hp[2]), a[4]);                         \
  a[5]=fmaf((HV), __high2float(_hp[2]), a[5]);                         \
  a[6]=fmaf((HV), __low2float (_hp[3]), a[6]);                         \
  a[7]=fmaf((HV), __high2float(_hp[3]), a[7]);                         \
}while(0)

// 512x512 matvec partial: rows [kcE*64,+64), cols [cgE*8,+8), sample s
// part layout: [kc][s][half][64 cg][4]  (stores are contiguous 16B-stride)
__device__ __forceinline__ void dot512(const float* __restrict__ vin,
                                       const __half* __restrict__ W,
                                       float* __restrict__ part,
                                       int cgE, int kcE, int s)
{
  float a[8];
  #pragma unroll
  for (int i=0;i<8;i++) a[i]=0.f;
  const int r0 = kcE*64;
  #pragma unroll 4
  for (int i=0;i<16;i++){
    const int r = r0 + i*4;
    float4 h4 = *reinterpret_cast<const float4*>(vin + r);
    uint4 u0 = *reinterpret_cast<const uint4*>(W + (size_t)(r+0)*512 + cgE*8);
    uint4 u1 = *reinterpret_cast<const uint4*>(W + (size_t)(r+1)*512 + cgE*8);
    uint4 u2 = *reinterpret_cast<const uint4*>(W + (size_t)(r+2)*512 + cgE*8);
    uint4 u3 = *reinterpret_cast<const uint4*>(W + (size_t)(r+3)*512 + cgE*8);
    FMA8(h4.x, u0); FMA8(h4.y, u1); FMA8(h4.z, u2); FMA8(h4.w, u3);
  }
  float* pb = part + kcE*1024 + s*512 + cgE*4;
  *(float4*)(pb)     = make_float4(a[0],a[1],a[2],a[3]);
  *(float4*)(pb+256) = make_float4(a[4],a[5],a[6],a[7]);
}

__device__ __forceinline__ float red8(const float* __restrict__ part, int s, int j){
  const int off = s*512 + ((j&4)<<6) + ((j>>3)<<2) + (j&3);
  float r = 0.f;
  #pragma unroll
  for (int q=0;q<8;q++) r += part[q*1024 + off];
  return r;
}

// gates: [x(128);h(512)] @ Wg(640x2048); cols [cgG*8,+8), K split in 2 halves
__device__ __forceinline__ void dot640(const float* __restrict__ shx,
                                       const float* __restrict__ shh,
                                       const __half* __restrict__ W,
                                       float* __restrict__ part2,
                                       int cgG, int kcG, int s)
{
  float a[8];
  #pragma unroll
  for (int i=0;i<8;i++) a[i]=0.f;
  if (kcG == 0){
    #pragma unroll 4
    for (int i=0;i<32;i++){
      const int r = i*4;
      float4 h4 = *reinterpret_cast<const float4*>(shx + s*128 + r);
      uint4 u0 = *reinterpret_cast<const uint4*>(W + (size_t)(r+0)*2048 + cgG*8);
      uint4 u1 = *reinterpret_cast<const uint4*>(W + (size_t)(r+1)*2048 + cgG*8);
      uint4 u2 = *reinterpret_cast<const uint4*>(W + (size_t)(r+2)*2048 + cgG*8);
      uint4 u3 = *reinterpret_cast<const uint4*>(W + (size_t)(r+3)*2048 + cgG*8);
      FMA8(h4.x, u0); FMA8(h4.y, u1); FMA8(h4.z, u2); FMA8(h4.w, u3);
    }
    #pragma unroll 4
    for (int i=0;i<48;i++){
      const int r = i*4;
      float4 h4 = *reinterpret_cast<const float4*>(shh + s*512 + r);
      uint4 u0 = *reinterpret_cast<const uint4*>(W + (size_t)(128+r+0)*2048 + cgG*8);
      uint4 u1 = *reinterpret_cast<const uint4*>(W + (size_t)(128+r+1)*2048 + cgG*8);
      uint4 u2 = *reinterpret_cast<const uint4*>(W + (size_t)(128+r+2)*2048 + cgG*8);
      uint4 u3 = *reinterpret_cast<const uint4*>(W + (size_t)(128+r+3)*2048 + cgG*8);
      FMA8(h4.x, u0); FMA8(h4.y, u1); FMA8(h4.z, u2); FMA8(h4.w, u3);
    }
  } else {
    #pragma unroll 4
    for (int i=0;i<80;i++){
      const int r = 192 + i*4;
      float4 h4 = *reinterpret_cast<const float4*>(shh + s*512 + r);
      uint4 u0 = *reinterpret_cast<const uint4*>(W + (size_t)(128+r+0)*2048 + cgG*8);
      uint4 u1 = *reinterpret_cast<const uint4*>(W + (size_t)(128+r+1)*2048 + cgG*8);
      uint4 u2 = *reinterpret_cast<const uint4*>(W + (size_t)(128+r+2)*2048 + cgG*8);
      uint4 u3 = *reinterpret_cast<const uint4*>(W + (size_t)(128+r+3)*2048 + cgG*8);
      FMA8(h4.x, u0); FMA8(h4.y, u1); FMA8(h4.z, u2); FMA8(h4.w, u3);
    }
  }
  float* pb = part2 + kcG*4096 + s*2048 + cgG*4;
  *(float4*)(pb)      = make_float4(a[0],a[1],a[2],a[3]);
  *(float4*)(pb+1024) = make_float4(a[4],a[5],a[6],a[7]);
}

// Wp2 (512x128): rows [kc2*16,+16), cols [cg4*8,+8)
__device__ __forceinline__ void dotp2(const float* __restrict__ vin,
                                      const __half* __restrict__ W,
                                      float* __restrict__ part,
                                      int cg4, int kc2, int s)
{
  float a[8];
  #pragma unroll
  for (int i=0;i<8;i++) a[i]=0.f;
  const int r0 = kc2*16;
  #pragma unroll
  for (int i=0;i<4;i++){
    const int r = r0 + i*4;
    float4 h4 = *reinterpret_cast<const float4*>(vin + r);
    uint4 u0 = *reinterpret_cast<const uint4*>(W + (size_t)(r+0)*128 + cg4*8);
    uint4 u1 = *reinterpret_cast<const uint4*>(W + (size_t)(r+1)*128 + cg4*8);
    uint4 u2 = *reinterpret_cast<const uint4*>(W + (size_t)(r+2)*128 + cg4*8);
    uint4 u3 = *reinterpret_cast<const uint4*>(W + (size_t)(r+3)*128 + cg4*8);
    FMA8(h4.x, u0); FMA8(h4.y, u1); FMA8(h4.z, u2); FMA8(h4.w, u3);
  }
  float* pb = part + kc2*256 + s*128 + cg4*4;
  *(float4*)(pb)    = make_float4(a[0],a[1],a[2],a[3]);
  *(float4*)(pb+64) = make_float4(a[4],a[5],a[6],a[7]);
}

__global__ __launch_bounds__(NT) void k_main(
  const float* __restrict__ X, const float* __restrict__ Mm,
  const int* __restrict__ pos, const __half* __restrict__ Wh,
  const float* __restrict__ bi_, const float* __restrict__ bf_,
  const float* __restrict__ bo_, const float* __restrict__ bc_,
  const float* __restrict__ b1_, const float* __restrict__ b2_,
  const float* __restrict__ bp1_, const float* __restrict__ bp2_,
  float* __restrict__ acc, int* __restrict__ ctr)
{
  const __half* W1h  = Wh;
  const __half* W2h  = Wh + 262144;
  const __half* Wp1h = Wh + 524288;
  const __half* Wp2h = Wh + 786432;
  const __half* Wgh  = Wh + 851968;

  const int t   = threadIdx.x;
  const int b   = blockIdx.x;
  const int s   = t >> 9;           // sample within pair (wave-uniform)
  const int j   = t & 511;          // hidden index
  const int cgE = t & 63;           // 8-col group (Euler/p1)
  const int kcE = (t >> 6) & 7;     // K chunk of 64
  const int cgG = t & 255;          // 8-col group (gates, 2048 cols)
  const int kcG = (t >> 8) & 1;     // K half
  const int cg4 = t & 15;           // 8-col group (p2, 128 cols)
  const int kc2 = (t >> 4) & 31;    // K chunk of 16

  __shared__ float sh_h[2*Hn];
  __shared__ float sh_c[2*Hn];
  __shared__ float sh_t[2*Hn];
  __shared__ float sh_x[2*Dn];
  __shared__ float part [8*1024];   // 32KB
  __shared__ float part2[2*4096];   // 32KB (gates)
  __shared__ float red[32];

  sh_h[t] = 0.f;
  sh_c[t] = 0.f;

  const float vb1 = b1_[j], vb2 = b2_[j], vbp1 = bp1_[j];
  const float vgi = bi_[j], vgf = bf_[j], vgo = bo_[j], vgc = bc_[j];
  float vbp2 = 0.f;
  if (t < 2*Dn) vbp2 = bp2_[t & (Dn-1)];

  float loss_loc = 0.f, m_loc = 0.f;

  for (int k=0;k<Kn;k++){
    soft_sync(ctr + k, NB);               // phase-lock all blocks per event
    const int e0 = pos[(k<<9) + 2*b];
    const int e1 = pos[(k<<9) + 2*b + 1];

    // ---- 2 Euler steps (unconditional, both samples) ----
    for (int st=0; st<2; st++){
      dot512(sh_h + s*512, W1h, part, cgE, kcE, s);
      __syncthreads();
      sh_t[t] = tanhf(red8(part, s, j) + vb1);
      __syncthreads();
      dot512(sh_t + s*512, W2h, part, cgE, kcE, s);
      __syncthreads();
      sh_h[t] += DT_C * (red8(part, s, j) + vb2);
      __syncthreads();
    }

    // stage X rows (zeros for unobserved sample) — overlaps Wp1 sweep
    if (t < 2*Dn){
      const int es2 = (t >> 7) ? e1 : e0;
      float v = 0.f;
      if (es2 >= 0) v = X[((size_t)(k*En+es2))*Dn + (t & (Dn-1))];
      sh_x[t] = v;
    }
    // p_model layer 1 (unconditional)
    dot512(sh_h + s*512, Wp1h, part, cgE, kcE, s);
    __syncthreads();
    sh_t[t] = fmaxf(red8(part, s, j) + vbp1, 0.f);
    __syncthreads();
    // p_model layer 2 (unconditional)
    dotp2(sh_t + s*512, Wp2h, part, cg4, kc2, s);
    __syncthreads();
    // loss tail (masked); overlaps gate sweep below (disjoint LDS buffers)
    if (t < 2*Dn){
      const int d = t & (Dn-1);
      const int es2 = (t >> 7) ? e1 : e0;
      if (es2 >= 0){
        const int off2 = ((t>>7))*128 + ((d&4)<<4) + ((d>>3)<<2) + (d&3);
        float p = vbp2;
        #pragma unroll
        for (int q=0;q<32;q++) p += part[q*256 + off2];
        float m  = Mm[((size_t)(k*En+es2))*Dn + d];
        loss_loc += fabsf(sh_x[t] - p) * m;
        m_loc    += m;
      }
    }

    // LSTM gates (unconditional sweep; dead at last event)
    if (k < Kn-1){
      dot640(sh_x, sh_h, Wgh, part2, cgG, kcG, s);
      __syncthreads();
      const int es = s ? e1 : e0;
      if (es >= 0){
        const int base = s*2048 + ((j&4)<<8) + ((j>>3)<<2) + (j&3);
        float pi = part2[base      ] + part2[4096 + base      ];
        float pf = part2[base + 256] + part2[4096 + base + 256];
        float po = part2[base + 512] + part2[4096 + base + 512];
        float pc = part2[base + 768] + part2[4096 + base + 768];
        float ig = sigm(pi + vgi), fg = sigm(pf + vgf);
        float og = sigm(po + vgo), ct = tanhf(pc + vgc);
        float cn = fg*sh_c[t] + ig*ct;
        sh_c[t] = cn;
        sh_h[t] = og * tanhf(cn);
      }
      // next event's soft_sync bars cover the sh_h/sh_c writes
    }
  }

  // block reduction -> global atomics
  #pragma unroll
  for (int off=32; off>0; off>>=1){
    loss_loc += __shfl_down(loss_loc, off);
    m_loc    += __shfl_down(m_loc, off);
  }
  const int wid = t >> 6, lane = t & 63;
  if (lane == 0){ red[wid] = loss_loc; red[16+wid] = m_loc; }
  __syncthreads();
  if (t == 0){
    float L = 0.f, Mt = 0.f;
    #pragma unroll
    for (int w2=0; w2<16; w2++){ L += red[w2]; Mt += red[16+w2]; }
    atomicAdd(acc+0, L);
    atomicAdd(acc+1, Mt);
  }
}

__global__ void k_fin(const float* __restrict__ acc, float* __restrict__ out){
  if (threadIdx.x == 0){
    out[0] = acc[0];
    out[1] = acc[0]/acc[1];
  }
}

extern "C" void kernel_launch(void* const* d_in, const int* in_sizes, int n_in,
                              void* d_out, int out_size, void* d_ws, size_t ws_size,
                              hipStream_t stream)
{
  const float* X   = (const float*)d_in[0];
  const float* Mm  = (const float*)d_in[1];
  const int*  bidx = (const int*)d_in[2];
  // d_in[3] = sample_idx (unused, arange)
  const float* Wi  = (const float*)d_in[4];
  const float* bi  = (const float*)d_in[5];
  const float* Wf  = (const float*)d_in[6];
  const float* bff = (const float*)d_in[7];
  const float* Wo  = (const float*)d_in[8];
  const float* bo  = (const float*)d_in[9];
  const float* Wc  = (const float*)d_in[10];
  const float* bc  = (const float*)d_in[11];
  const float* W1  = (const float*)d_in[12];
  const float* b1  = (const float*)d_in[13];
  const float* W2  = (const float*)d_in[14];
  const float* b2  = (const float*)d_in[15];
  const float* Wp1 = (const float*)d_in[16];
  const float* bp1 = (const float*)d_in[17];
  const float* Wp2 = (const float*)d_in[18];
  const float* bp2 = (const float*)d_in[19];

  char* ws = (char*)d_ws;
  int*    pos = (int*)ws;
  float*  acc = (float*)(ws + 131072);
  int*    ctr = (int*)(ws + 131088);
  __half* wh  = (__half*)(ws + 131584);

  k_init   <<<(Kn*Bn + 255)/256, 256, 0, stream>>>(pos, acc, ctr);
  k_scatter<<<(Kn*En + 255)/256, 256, 0, stream>>>(bidx, pos);

  k_cvt<<<(Hn*Hn + 255)/256, 256, 0, stream>>>(W1,  wh + 0,      Hn*Hn);
  k_cvt<<<(Hn*Hn + 255)/256, 256, 0, stream>>>(W2,  wh + 262144, Hn*Hn);
  k_cvt<<<(Hn*Hn + 255)/256, 256, 0, stream>>>(Wp1, wh + 524288, Hn*Hn);
  k_cvt<<<(Hn*Dn + 255)/256, 256, 0, stream>>>(Wp2, wh + 786432, Hn*Dn);
  k_cvt_g<<<(640*512 + 255)/256, 256, 0, stream>>>(Wi, wh + 851968, 0);
  k_cvt_g<<<(640*512 + 255)/256, 256, 0, stream>>>(Wf, wh + 851968, 1);
  k_cvt_g<<<(640*512 + 255)/256, 256, 0, stream>>>(Wo, wh + 851968, 2);
  k_cvt_g<<<(640*512 + 255)/256, 256, 0, stream>>>(Wc, wh + 851968, 3);

  k_main<<<NB, NT, 0, stream>>>(X, Mm, pos, wh,
                                bi, bff, bo, bc, b1, b2, bp1, bp2, acc, ctr);
  k_fin<<<1, 64, 0, stream>>>(acc, (float*)d_out);
}

// Round 5
// 3299.676 us; speedup vs baseline: 2.4779x; 2.4779x over previous
//
#include <hip/hip_runtime.h>
#include <hip/hip_fp16.h>
#include <stdint.h>

#define Kn 64
#define En 256
#define Bn 512
#define Hn 512
#define Dn 128
#define NBLK 256
#define NTH  256
#define DT_C 0.05f

// ws layout (bytes):
//   0        pos   int[Kn*Bn]           (128 KB)
//   131072   acc   float[2]
//   131200   ctr   int, 32 groups x 128B stride (4 KB)
//   1048576  Hf16  __half[512][512]     (512 KB)
//   1572864  Tf16  __half[512][512]     (512 KB)
//   2097152  Gpre  __half[512][2048]    (2 MB)
//   4194304  WF    frag-swizzled f16 weights (4.33 MB)
// WF half-offsets: W1 0, W2 262144, Wp1 524288, Wp2 786432, Wg 851968
//   frag layout per matrix: idx = ((coltile*KT + ktile)*64 + lane)*8 + e
//   element = W[ktile*32 + (lane>>4)*8 + e][coltile*16 + (lane&15)]

typedef _Float16 f16x8 __attribute__((ext_vector_type(8)));
typedef float    f32x4 __attribute__((ext_vector_type(4)));
typedef unsigned long long u64;

__device__ __forceinline__ float sigm(float x){ return 1.0f/(1.0f + __expf(-x)); }

__device__ __forceinline__ u64 ald(const u64* p){
  return __hip_atomic_load(p, __ATOMIC_RELAXED, __HIP_MEMORY_SCOPE_AGENT);
}
__device__ __forceinline__ void ast(u64* p, u64 v){
  __hip_atomic_store(p, v, __ATOMIC_RELAXED, __HIP_MEMORY_SCOPE_AGENT);
}

union HU { __half h[8]; u64 q[2]; uint32_t w[4]; };
union H4 { __half h[4]; u64 q; uint32_t w[2]; };

__global__ void k_init(int* __restrict__ pos, float* __restrict__ acc,
                       int* __restrict__ ctr, uint32_t* __restrict__ hf){
  int i = blockIdx.x*blockDim.x + threadIdx.x;
  if (i < Kn*Bn) pos[i] = -1;
  if (i < 2) acc[i] = 0.0f;
  if (i < 1024) ctr[i] = 0;                 // whole 4KB ctr region
  if (i < Hn*Hn/2) hf[i] = 0;               // zero Hf16 (2 halves per u32)
}

__global__ void k_scatter(const int* __restrict__ bidx, int* __restrict__ pos){
  int i = blockIdx.x*blockDim.x + threadIdx.x;
  if (i < Kn*En){
    int k = i >> 8;
    int e = i & (En-1);
    pos[(k << 9) | bidx[i]] = e;
  }
}

// frag-swizzle convert: dst[i] layout as documented above. N = src col count.
__global__ void k_cvt_frag(const float* __restrict__ src, __half* __restrict__ dst,
                           int KT, int N, int n){
  int i = blockIdx.x*blockDim.x + threadIdx.x;
  if (i >= n) return;
  int C = i / (KT*512);
  int r = i % (KT*512);
  int T = r >> 9;
  int q = r & 511;
  int l = q >> 3, e = q & 7;
  int srow = T*32 + ((l>>4)<<3) + e;
  int scol = C*16 + (l&15);
  dst[i] = __float2half(src[(size_t)srow*N + scol]);
}

// 8-block group barrier (device-scope). All 256 blocks are co-resident
// (grid 256, 4 waves, <64KB LDS), so the spin always makes progress.
__device__ __forceinline__ void gsync(int* c, int tgt){
  __syncthreads();
  if (threadIdx.x == 0){
    __hip_atomic_fetch_add(c, 1, __ATOMIC_RELEASE, __HIP_MEMORY_SCOPE_AGENT);
    while (__hip_atomic_load(c, __ATOMIC_ACQUIRE, __HIP_MEMORY_SCOPE_AGENT) < tgt)
      __builtin_amdgcn_s_sleep(1);
  }
  __syncthreads();
}

__global__ __launch_bounds__(NTH) void k_main(
  const float* __restrict__ X, const float* __restrict__ Mm,
  const int* __restrict__ pos, const __half* __restrict__ WF,
  __half* __restrict__ Hf, __half* __restrict__ Tf, __half* __restrict__ Gp,
  const float* __restrict__ bi_, const float* __restrict__ bf_,
  const float* __restrict__ bo_, const float* __restrict__ bc_,
  const float* __restrict__ b1_, const float* __restrict__ b2_,
  const float* __restrict__ bp1_, const float* __restrict__ bp2_,
  float* __restrict__ acc, int* __restrict__ ctrbase)
{
  const __half* W1F  = WF;
  const __half* W2F  = WF + 262144;
  const __half* Wp1F = WF + 524288;
  const __half* Wp2F = WF + 786432;
  const __half* WgF  = WF + 851968;

  const int t    = threadIdx.x;
  const int bid  = blockIdx.x;
  // group members share bid&7 (likely same XCD; correctness independent of it)
  const int g    = (bid & 7)*4 + ((bid >> 3) & 3);   // 0..31
  const int s    = bid >> 5;                         // slice 0..7
  const int w    = t >> 6;                           // wave 0..3
  const int lane = t & 63;

  int* ctr = ctrbase + g*32;                         // 128B-strided counter

  __shared__ __align__(16) __half Afrag[16*512];     // 16KB [ktile][lane][8]
  __shared__ __align__(16) __half Xfrag[4*512];      // 4KB
  __shared__ __align__(16) float  outb[20*256];      // 20KB out tiles
  __shared__ __align__(16) __half gstage[16*256];    // 8KB [row][gate][64]
  __shared__ float redbuf[8];

  // per-thread owned state: row = t>>4, cols s*64 + (t&15)*4 .. +3
  const int row = t >> 4;
  const int q4  = t & 15;
  const int sc  = s*64 + q4*4;
  float Hreg[4] = {0,0,0,0};
  float Creg[4] = {0,0,0,0};
  float vb1[4], vb2[4], vbp1[4], vbi[4], vbf[4], vbo[4], vbc[4];
  #pragma unroll
  for (int i=0;i<4;i++){
    vb1[i]=b1_[sc+i]; vb2[i]=b2_[sc+i]; vbp1[i]=bp1_[sc+i];
    vbi[i]=bi_[sc+i]; vbf[i]=bf_[sc+i]; vbo[i]=bo_[sc+i]; vbc[i]=bc_[sc+i];
  }
  const float vbp2 = bp2_[s*16 + q4];

  float loss_loc = 0.f, m_loc = 0.f;
  int round = 0;

  const int grow = g*16 + row;          // this thread's global sample row

  for (int k=0; k<Kn; k++){
    const int epos = pos[(k<<9) + grow];         // event slot of own row (or -1)

    // ================= 4 Euler phases =================
    #pragma unroll 1
    for (int ph=0; ph<4; ph++){
      const __half* src  = (ph & 1) ? Tf : Hf;
      const __half* wmat = (ph & 1) ? W2F : W1F;
      // stage A (16 rows x 512) into frag layout
      {
        const int ar = t & 15, ch = t >> 4;
        const u64* sp = (const u64*)(src + ((size_t)(g*16+ar))*512 + ch*32);
        u64 v[8];
        #pragma unroll
        for (int i=0;i<8;i++) v[i] = ald(sp+i);
        #pragma unroll
        for (int kg=0;kg<4;kg++){
          u64* d = (u64*)(Afrag + ch*512 + (ar + 16*kg)*8);
          d[0] = v[2*kg]; d[1] = v[2*kg+1];
        }
      }
      __syncthreads();
      // mfma: wave w -> coltile s*4+w, 16 ktiles
      {
        const __half* wb = wmat + (size_t)(s*4 + w)*16*512;
        f32x4 a4 = {0,0,0,0};
        #pragma unroll 4
        for (int kt=0; kt<16; kt++){
          f16x8 a = *(const f16x8*)(Afrag + kt*512 + lane*8);
          f16x8 b = *(const f16x8*)(wb + kt*512 + lane*8);
          a4 = __builtin_amdgcn_mfma_f32_16x16x32_f16(a, b, a4, 0,0,0);
        }
        float* o = outb + w*256 + ((lane>>4)*4)*16 + (lane&15);
        o[0]=a4[0]; o[16]=a4[1]; o[32]=a4[2]; o[48]=a4[3];
      }
      __syncthreads();
      // transform + store (thread t: row, cols q4*4..+3)
      {
        const float* o = outb + (q4>>2)*256 + row*16 + (q4&3)*4;
        float v0=o[0], v1=o[1], v2=o[2], v3=o[3];
        HU u;
        if (!(ph & 1)){       // -> T = tanh(. + b1)
          u.h[0]=__float2half(tanhf(v0+vb1[0])); u.h[1]=__float2half(tanhf(v1+vb1[1]));
          u.h[2]=__float2half(tanhf(v2+vb1[2])); u.h[3]=__float2half(tanhf(v3+vb1[3]));
          ast((u64*)(Tf + (size_t)grow*512 + sc), u.q[0]);
        } else {              // H += dt*(. + b2)
          Hreg[0] += DT_C*(v0+vb2[0]); Hreg[1] += DT_C*(v1+vb2[1]);
          Hreg[2] += DT_C*(v2+vb2[2]); Hreg[3] += DT_C*(v3+vb2[3]);
          u.h[0]=__float2half(Hreg[0]); u.h[1]=__float2half(Hreg[1]);
          u.h[2]=__float2half(Hreg[2]); u.h[3]=__float2half(Hreg[3]);
          ast((u64*)(Hf + (size_t)grow*512 + sc), u.q[0]);
        }
      }
      gsync(ctr, 8*(++round));
    }

    // ================= phase 5: P1 + gate dots =================
    {
      // stage A = H
      {
        const int ar = t & 15, ch = t >> 4;
        const u64* sp = (const u64*)(Hf + ((size_t)(g*16+ar))*512 + ch*32);
        u64 v[8];
        #pragma unroll
        for (int i=0;i<8;i++) v[i] = ald(sp+i);
        #pragma unroll
        for (int kg=0;kg<4;kg++){
          u64* d = (u64*)(Afrag + ch*512 + (ar + 16*kg)*8);
          d[0] = v[2*kg]; d[1] = v[2*kg+1];
        }
      }
      // stage X rows (zero for unobserved)
      if (t < 64){
        const int ar = t & 15, ch = t >> 4;       // ch = ktile 0..3
        const int e = pos[(k<<9) + g*16 + ar];
        float xv[32];
        if (e >= 0){
          const float4* xp = (const float4*)(X + ((size_t)(k*En+e))*Dn + ch*32);
          #pragma unroll
          for (int i=0;i<8;i++){
            float4 f = xp[i];
            xv[4*i]=f.x; xv[4*i+1]=f.y; xv[4*i+2]=f.z; xv[4*i+3]=f.w;
          }
        } else {
          #pragma unroll
          for (int i=0;i<32;i++) xv[i]=0.f;
        }
        #pragma unroll
        for (int kg=0;kg<4;kg++){
          HU u;
          #pragma unroll
          for (int e8=0;e8<8;e8++) u.h[e8] = __float2half(xv[kg*8+e8]);
          u64* d = (u64*)(Xfrag + ch*512 + (ar + 16*kg)*8);
          d[0] = u.q[0]; d[1] = u.q[1];
        }
      }
      __syncthreads();
      // P1: coltile s*4+w of Wp1 -> slot 16+w
      {
        const __half* wb = Wp1F + (size_t)(s*4 + w)*16*512;
        f32x4 a4 = {0,0,0,0};
        #pragma unroll 4
        for (int kt=0; kt<16; kt++){
          f16x8 a = *(const f16x8*)(Afrag + kt*512 + lane*8);
          f16x8 b = *(const f16x8*)(wb + kt*512 + lane*8);
          a4 = __builtin_amdgcn_mfma_f32_16x16x32_f16(a, b, a4, 0,0,0);
        }
        float* o = outb + (16+w)*256 + ((lane>>4)*4)*16 + (lane&15);
        o[0]=a4[0]; o[16]=a4[1]; o[32]=a4[2]; o[48]=a4[3];
      }
      // gates: 4 coltiles per wave, K=640 (4 X-ktiles + 16 H-ktiles)
      #pragma unroll 1
      for (int i=0;i<4;i++){
        const int Cg = s*16 + w*4 + i;
        const __half* wb = WgF + (size_t)Cg*20*512;
        f32x4 a4 = {0,0,0,0};
        #pragma unroll 4
        for (int kt=0; kt<4; kt++){
          f16x8 a = *(const f16x8*)(Xfrag + kt*512 + lane*8);
          f16x8 b = *(const f16x8*)(wb + kt*512 + lane*8);
          a4 = __builtin_amdgcn_mfma_f32_16x16x32_f16(a, b, a4, 0,0,0);
        }
        #pragma unroll 4
        for (int kt=4; kt<20; kt++){
          f16x8 a = *(const f16x8*)(Afrag + (kt-4)*512 + lane*8);
          f16x8 b = *(const f16x8*)(wb + kt*512 + lane*8);
          a4 = __builtin_amdgcn_mfma_f32_16x16x32_f16(a, b, a4, 0,0,0);
        }
        float* o = outb + (w*4+i)*256 + ((lane>>4)*4)*16 + (lane&15);
        o[0]=a4[0]; o[16]=a4[1]; o[32]=a4[2]; o[48]=a4[3];
      }
      __syncthreads();
      // store T (P1 result, relu)
      {
        const float* o = outb + (16+(q4>>2))*256 + row*16 + (q4&3)*4;
        HU u;
        u.h[0]=__float2half(fmaxf(o[0]+vbp1[0],0.f));
        u.h[1]=__float2half(fmaxf(o[1]+vbp1[1],0.f));
        u.h[2]=__float2half(fmaxf(o[2]+vbp1[2],0.f));
        u.h[3]=__float2half(fmaxf(o[3]+vbp1[3],0.f));
        ast((u64*)(Tf + (size_t)grow*512 + sc), u.q[0]);
      }
      // store gate pre-acts: thread t -> tile q4, row, 16 cols
      {
        const float* o = outb + q4*256 + row*16;
        HU u0, u1;
        #pragma unroll
        for (int c=0;c<8;c++){ u0.h[c]=__float2half(o[c]); u1.h[c]=__float2half(o[8+c]); }
        u64* d = (u64*)(Gp + (size_t)grow*2048 + (s*16+q4)*16);
        ast(d, u0.q[0]); ast(d+1, u0.q[1]); ast(d+2, u1.q[0]); ast(d+3, u1.q[1]);
      }
      gsync(ctr, 8*(++round));
    }

    // ================= phase 6: P2 + loss + LSTM update =================
    {
      // stage A = T
      {
        const int ar = t & 15, ch = t >> 4;
        const u64* sp = (const u64*)(Tf + ((size_t)(g*16+ar))*512 + ch*32);
        u64 v[8];
        #pragma unroll
        for (int i=0;i<8;i++) v[i] = ald(sp+i);
        #pragma unroll
        for (int kg=0;kg<4;kg++){
          u64* d = (u64*)(Afrag + ch*512 + (ar + 16*kg)*8);
          d[0] = v[2*kg]; d[1] = v[2*kg+1];
        }
      }
      // stage gate pre-acts for own h-cols: [row][gate][64]
      {
        const int gr = t >> 4, gate = (t&15) >> 2, c16 = (t&3)*16;
        const u64* gp = (const u64*)(Gp + ((size_t)(g*16+gr))*2048 + gate*512 + s*64 + c16);
        u64 a0=ald(gp), a1=ald(gp+1), a2=ald(gp+2), a3=ald(gp+3);
        u64* d = (u64*)(gstage + gr*256 + gate*64 + c16);
        d[0]=a0; d[1]=a1; d[2]=a2; d[3]=a3;
      }
      __syncthreads();
      // P2: coltile s of Wp2, wave w does ktiles w*4..+3 -> slot w
      {
        const __half* wb = Wp2F + (size_t)s*16*512;
        f32x4 a4 = {0,0,0,0};
        #pragma unroll
        for (int kt2=0; kt2<4; kt2++){
          const int kt = w*4 + kt2;
          f16x8 a = *(const f16x8*)(Afrag + kt*512 + lane*8);
          f16x8 b = *(const f16x8*)(wb + kt*512 + lane*8);
          a4 = __builtin_amdgcn_mfma_f32_16x16x32_f16(a, b, a4, 0,0,0);
        }
        float* o = outb + w*256 + ((lane>>4)*4)*16 + (lane&15);
        o[0]=a4[0]; o[16]=a4[1]; o[32]=a4[2]; o[48]=a4[3];
      }
      // LSTM update from gstage (own rows/cols, obs-masked)
      if (epos >= 0){
        H4 ui,uf,uo,uc;
        ui.q = *(const u64*)(gstage + row*256 +   0 + q4*4);
        uf.q = *(const u64*)(gstage + row*256 +  64 + q4*4);
        uo.q = *(const u64*)(gstage + row*256 + 128 + q4*4);
        uc.q = *(const u64*)(gstage + row*256 + 192 + q4*4);
        HU hu;
        #pragma unroll
        for (int i=0;i<4;i++){
          float ig = sigm(__half2float(ui.h[i]) + vbi[i]);
          float fg = sigm(__half2float(uf.h[i]) + vbf[i]);
          float og = sigm(__half2float(uo.h[i]) + vbo[i]);
          float ct = tanhf(__half2float(uc.h[i]) + vbc[i]);
          Creg[i] = fg*Creg[i] + ig*ct;
          Hreg[i] = og*tanhf(Creg[i]);
          hu.h[i] = __float2half(Hreg[i]);
        }
        ast((u64*)(Hf + (size_t)grow*512 + sc), hu.q[0]);
      }
      __syncthreads();
      // loss: thread t -> (row, col=q4) of p
      if (epos >= 0){
        float p = outb[row*16+q4] + outb[256+row*16+q4]
                + outb[512+row*16+q4] + outb[768+row*16+q4] + vbp2;
        const int d = s*16 + q4;
        float xo = X[((size_t)(k*En+epos))*Dn + d];
        float mo = Mm[((size_t)(k*En+epos))*Dn + d];
        loss_loc += fabsf(xo - p)*mo;
        m_loc    += mo;
      }
      gsync(ctr, 8*(++round));
    }
  }

  // block reduction -> global atomics
  #pragma unroll
  for (int off=32; off>0; off>>=1){
    loss_loc += __shfl_down(loss_loc, off);
    m_loc    += __shfl_down(m_loc, off);
  }
  if (lane == 0){ redbuf[w] = loss_loc; redbuf[4+w] = m_loc; }
  __syncthreads();
  if (t == 0){
    atomicAdd(acc+0, redbuf[0]+redbuf[1]+redbuf[2]+redbuf[3]);
    atomicAdd(acc+1, redbuf[4]+redbuf[5]+redbuf[6]+redbuf[7]);
  }
}

__global__ void k_fin(const float* __restrict__ acc, float* __restrict__ out){
  if (threadIdx.x == 0){
    out[0] = acc[0];
    out[1] = acc[0]/acc[1];
  }
}

extern "C" void kernel_launch(void* const* d_in, const int* in_sizes, int n_in,
                              void* d_out, int out_size, void* d_ws, size_t ws_size,
                              hipStream_t stream)
{
  const float* X   = (const float*)d_in[0];
  const float* Mm  = (const float*)d_in[1];
  const int*  bidx = (const int*)d_in[2];
  const float* Wi  = (const float*)d_in[4];
  const float* bi  = (const float*)d_in[5];
  const float* Wf  = (const float*)d_in[6];
  const float* bff = (const float*)d_in[7];
  const float* Wo  = (const float*)d_in[8];
  const float* bo  = (const float*)d_in[9];
  const float* Wc  = (const float*)d_in[10];
  const float* bc  = (const float*)d_in[11];
  const float* W1  = (const float*)d_in[12];
  const float* b1  = (const float*)d_in[13];
  const float* W2  = (const float*)d_in[14];
  const float* b2  = (const float*)d_in[15];
  const float* Wp1 = (const float*)d_in[16];
  const float* bp1 = (const float*)d_in[17];
  const float* Wp2 = (const float*)d_in[18];
  const float* bp2 = (const float*)d_in[19];

  char* ws = (char*)d_ws;
  int*    pos = (int*)ws;
  float*  acc = (float*)(ws + 131072);
  int*    ctr = (int*)(ws + 131200);
  __half* Hf  = (__half*)(ws + 1048576);
  __half* Tf  = (__half*)(ws + 1572864);
  __half* Gp  = (__half*)(ws + 2097152);
  __half* WF  = (__half*)(ws + 4194304);

  k_init   <<<512, 256, 0, stream>>>(pos, acc, ctr, (uint32_t*)Hf);
  k_scatter<<<(Kn*En + 255)/256, 256, 0, stream>>>(bidx, pos);

  // frag-swizzle weight conversion
  k_cvt_frag<<<(262144+255)/256, 256, 0, stream>>>(W1,  WF,          16, 512, 262144);
  k_cvt_frag<<<(262144+255)/256, 256, 0, stream>>>(W2,  WF + 262144, 16, 512, 262144);
  k_cvt_frag<<<(262144+255)/256, 256, 0, stream>>>(Wp1, WF + 524288, 16, 512, 262144);
  k_cvt_frag<<<(65536 +255)/256, 256, 0, stream>>>(Wp2, WF + 786432, 16, 128, 65536);
  k_cvt_frag<<<(327680+255)/256, 256, 0, stream>>>(Wi,  WF + 851968,            20, 512, 327680);
  k_cvt_frag<<<(327680+255)/256, 256, 0, stream>>>(Wf,  WF + 851968 + 327680,   20, 512, 327680);
  k_cvt_frag<<<(327680+255)/256, 256, 0, stream>>>(Wo,  WF + 851968 + 655360,   20, 512, 327680);
  k_cvt_frag<<<(327680+255)/256, 256, 0, stream>>>(Wc,  WF + 851968 + 983040,   20, 512, 327680);

  k_main<<<NBLK, NTH, 0, stream>>>(X, Mm, pos, WF, Hf, Tf, Gp,
                                   bi, bff, bo, bc, b1, b2, bp1, bp2, acc, ctr);
  k_fin<<<1, 64, 0, stream>>>(acc, (float*)d_out);
}

// Round 6
// 2113.764 us; speedup vs baseline: 3.8681x; 1.5610x over previous
//
#include <hip/hip_runtime.h>
#include <hip/hip_fp16.h>
#include <stdint.h>

#define Kn 64
#define En 256
#define Bn 512
#define Hn 512
#define Dn 128
#define NBLK 256
#define NTH  256
#define DT_C 0.05f

// ws layout (bytes):
//   0        pos   int[Kn*Bn]           (128 KB)
//   131072   acc   float[2]
//   131200   ctr   int, 32 groups x 128B stride (4 KB)
//   1048576  Hf16  __half[512][512]     (512 KB)
//   1572864  Tf16  __half[512][512]     (512 KB)
//   2097152  Gpre  __half[512][2048]    (2 MB)
//   4194304  WF    frag-swizzled f16 weights (4.33 MB)
// WF half-offsets: W1 0, W2 262144, Wp1 524288, Wp2 786432, Wg 851968
//   frag layout per matrix: idx = ((coltile*KT + ktile)*64 + lane)*8 + e
//   element = W[ktile*32 + (lane>>4)*8 + e][coltile*16 + (lane&15)]

typedef _Float16 f16x8 __attribute__((ext_vector_type(8)));
typedef float    f32x4 __attribute__((ext_vector_type(4)));
typedef unsigned long long u64;

__device__ __forceinline__ float sigm(float x){ return 1.0f/(1.0f + __expf(-x)); }

__device__ __forceinline__ u64 ald(const u64* p){
  return __hip_atomic_load(p, __ATOMIC_RELAXED, __HIP_MEMORY_SCOPE_AGENT);
}
__device__ __forceinline__ void ast(u64* p, u64 v){
  __hip_atomic_store(p, v, __ATOMIC_RELAXED, __HIP_MEMORY_SCOPE_AGENT);
}

union HU { __half h[8]; u64 q[2]; uint32_t w[4]; };
union H4 { __half h[4]; u64 q; uint32_t w[2]; };

__global__ void k_init(int* __restrict__ pos, float* __restrict__ acc,
                       int* __restrict__ ctr, uint32_t* __restrict__ hf){
  int i = blockIdx.x*blockDim.x + threadIdx.x;
  if (i < Kn*Bn) pos[i] = -1;
  if (i < 2) acc[i] = 0.0f;
  if (i < 1024) ctr[i] = 0;
  if (i < Hn*Hn/2) hf[i] = 0;
}

__global__ void k_scatter(const int* __restrict__ bidx, int* __restrict__ pos){
  int i = blockIdx.x*blockDim.x + threadIdx.x;
  if (i < Kn*En){
    int k = i >> 8;
    int e = i & (En-1);
    pos[(k << 9) | bidx[i]] = e;
  }
}

// frag-swizzle convert: dst[i] layout as documented above. N = src col count.
__global__ void k_cvt_frag(const float* __restrict__ src, __half* __restrict__ dst,
                           int KT, int N, int n){
  int i = blockIdx.x*blockDim.x + threadIdx.x;
  if (i >= n) return;
  int C = i / (KT*512);
  int r = i % (KT*512);
  int T = r >> 9;
  int q = r & 511;
  int l = q >> 3, e = q & 7;
  int srow = T*32 + ((l>>4)<<3) + e;
  int scol = C*16 + (l&15);
  dst[i] = __float2half(src[(size_t)srow*N + scol]);
}

// 8-block group barrier WITHOUT acq/rel cache fences (they wipe L2!).
// Ordering is hand-rolled: vmcnt(0) drains this thread's (coherent, sc1)
// data stores/loads to the coherence point before the flag-add; consumers'
// post-spin coherent loads are point-ordered after their flag observation.
// All 256 blocks are co-resident (grid 256 = #CUs, 1 block/CU).
__device__ __forceinline__ void gsync(int* c, int tgt){
  asm volatile("s_waitcnt vmcnt(0)" ::: "memory");
  __syncthreads();
  if (threadIdx.x == 0)
    __hip_atomic_fetch_add(c, 1, __ATOMIC_RELAXED, __HIP_MEMORY_SCOPE_AGENT);
  while (__hip_atomic_load(c, __ATOMIC_RELAXED, __HIP_MEMORY_SCOPE_AGENT) < tgt)
    __builtin_amdgcn_s_sleep(2);
  asm volatile("" ::: "memory");
}

__global__ __launch_bounds__(NTH) void k_main(
  const float* __restrict__ X, const float* __restrict__ Mm,
  const int* __restrict__ pos, const __half* __restrict__ WF,
  __half* __restrict__ Hf, __half* __restrict__ Tf, __half* __restrict__ Gp,
  const float* __restrict__ bi_, const float* __restrict__ bf_,
  const float* __restrict__ bo_, const float* __restrict__ bc_,
  const float* __restrict__ b1_, const float* __restrict__ b2_,
  const float* __restrict__ bp1_, const float* __restrict__ bp2_,
  float* __restrict__ acc, int* __restrict__ ctrbase)
{
  const __half* W1F  = WF;
  const __half* W2F  = WF + 262144;
  const __half* Wp1F = WF + 524288;
  const __half* Wp2F = WF + 786432;
  const __half* WgF  = WF + 851968;

  const int t    = threadIdx.x;
  const int bid  = blockIdx.x;
  // group members share bid&7 (same XCD under round-robin dispatch; perf only)
  const int g    = (bid & 7)*4 + ((bid >> 3) & 3);   // 0..31
  const int s    = bid >> 5;                         // slice 0..7
  const int w    = t >> 6;                           // wave 0..3
  const int lane = t & 63;

  int* ctr = ctrbase + g*32;

  __shared__ __align__(16) __half Afrag[16*512];     // 16KB
  __shared__ __align__(16) __half Xfrag[4*512];      // 4KB
  __shared__ __align__(16) float  outb[20*256];      // 20KB
  __shared__ __align__(16) __half gstage[16*256];    // 8KB
  __shared__ float redbuf[8];

  const int row = t >> 4;
  const int q4  = t & 15;
  const int sc  = s*64 + q4*4;
  float Hreg[4] = {0,0,0,0};
  float Creg[4] = {0,0,0,0};
  float vb1[4], vb2[4], vbp1[4], vbi[4], vbf[4], vbo[4], vbc[4];
  #pragma unroll
  for (int i=0;i<4;i++){
    vb1[i]=b1_[sc+i]; vb2[i]=b2_[sc+i]; vbp1[i]=bp1_[sc+i];
    vbi[i]=bi_[sc+i]; vbf[i]=bf_[sc+i]; vbo[i]=bo_[sc+i]; vbc[i]=bc_[sc+i];
  }
  const float vbp2 = bp2_[s*16 + q4];

  float loss_loc = 0.f, m_loc = 0.f;
  int round = 0;

  const int grow = g*16 + row;

  for (int k=0; k<Kn; k++){
    const int epos = pos[(k<<9) + grow];

    // ================= 4 Euler phases =================
    #pragma unroll 1
    for (int ph=0; ph<4; ph++){
      const __half* src  = (ph & 1) ? Tf : Hf;
      const __half* wmat = (ph & 1) ? W2F : W1F;
      {
        const int ar = t & 15, ch = t >> 4;
        const u64* sp = (const u64*)(src + ((size_t)(g*16+ar))*512 + ch*32);
        u64 v[8];
        #pragma unroll
        for (int i=0;i<8;i++) v[i] = ald(sp+i);
        #pragma unroll
        for (int kg=0;kg<4;kg++){
          u64* d = (u64*)(Afrag + ch*512 + (ar + 16*kg)*8);
          d[0] = v[2*kg]; d[1] = v[2*kg+1];
        }
      }
      __syncthreads();
      {
        const __half* wb = wmat + (size_t)(s*4 + w)*16*512;
        f32x4 a4 = {0,0,0,0};
        #pragma unroll 4
        for (int kt=0; kt<16; kt++){
          f16x8 a = *(const f16x8*)(Afrag + kt*512 + lane*8);
          f16x8 b = *(const f16x8*)(wb + kt*512 + lane*8);
          a4 = __builtin_amdgcn_mfma_f32_16x16x32_f16(a, b, a4, 0,0,0);
        }
        float* o = outb + w*256 + ((lane>>4)*4)*16 + (lane&15);
        o[0]=a4[0]; o[16]=a4[1]; o[32]=a4[2]; o[48]=a4[3];
      }
      __syncthreads();
      {
        const float* o = outb + (q4>>2)*256 + row*16 + (q4&3)*4;
        float v0=o[0], v1=o[1], v2=o[2], v3=o[3];
        HU u;
        if (!(ph & 1)){
          u.h[0]=__float2half(tanhf(v0+vb1[0])); u.h[1]=__float2half(tanhf(v1+vb1[1]));
          u.h[2]=__float2half(tanhf(v2+vb1[2])); u.h[3]=__float2half(tanhf(v3+vb1[3]));
          ast((u64*)(Tf + (size_t)grow*512 + sc), u.q[0]);
        } else {
          Hreg[0] += DT_C*(v0+vb2[0]); Hreg[1] += DT_C*(v1+vb2[1]);
          Hreg[2] += DT_C*(v2+vb2[2]); Hreg[3] += DT_C*(v3+vb2[3]);
          u.h[0]=__float2half(Hreg[0]); u.h[1]=__float2half(Hreg[1]);
          u.h[2]=__float2half(Hreg[2]); u.h[3]=__float2half(Hreg[3]);
          ast((u64*)(Hf + (size_t)grow*512 + sc), u.q[0]);
        }
      }
      gsync(ctr, 8*(++round));
    }

    // ================= phase 5: P1 + gate dots =================
    {
      {
        const int ar = t & 15, ch = t >> 4;
        const u64* sp = (const u64*)(Hf + ((size_t)(g*16+ar))*512 + ch*32);
        u64 v[8];
        #pragma unroll
        for (int i=0;i<8;i++) v[i] = ald(sp+i);
        #pragma unroll
        for (int kg=0;kg<4;kg++){
          u64* d = (u64*)(Afrag + ch*512 + (ar + 16*kg)*8);
          d[0] = v[2*kg]; d[1] = v[2*kg+1];
        }
      }
      if (t < 64){
        const int ar = t & 15, ch = t >> 4;
        const int e = pos[(k<<9) + g*16 + ar];
        float xv[32];
        if (e >= 0){
          const float4* xp = (const float4*)(X + ((size_t)(k*En+e))*Dn + ch*32);
          #pragma unroll
          for (int i=0;i<8;i++){
            float4 f = xp[i];
            xv[4*i]=f.x; xv[4*i+1]=f.y; xv[4*i+2]=f.z; xv[4*i+3]=f.w;
          }
        } else {
          #pragma unroll
          for (int i=0;i<32;i++) xv[i]=0.f;
        }
        #pragma unroll
        for (int kg=0;kg<4;kg++){
          HU u;
          #pragma unroll
          for (int e8=0;e8<8;e8++) u.h[e8] = __float2half(xv[kg*8+e8]);
          u64* d = (u64*)(Xfrag + ch*512 + (ar + 16*kg)*8);
          d[0] = u.q[0]; d[1] = u.q[1];
        }
      }
      __syncthreads();
      {
        const __half* wb = Wp1F + (size_t)(s*4 + w)*16*512;
        f32x4 a4 = {0,0,0,0};
        #pragma unroll 4
        for (int kt=0; kt<16; kt++){
          f16x8 a = *(const f16x8*)(Afrag + kt*512 + lane*8);
          f16x8 b = *(const f16x8*)(wb + kt*512 + lane*8);
          a4 = __builtin_amdgcn_mfma_f32_16x16x32_f16(a, b, a4, 0,0,0);
        }
        float* o = outb + (16+w)*256 + ((lane>>4)*4)*16 + (lane&15);
        o[0]=a4[0]; o[16]=a4[1]; o[32]=a4[2]; o[48]=a4[3];
      }
      #pragma unroll 1
      for (int i=0;i<4;i++){
        const int Cg = s*16 + w*4 + i;
        const __half* wb = WgF + (size_t)Cg*20*512;
        f32x4 a4 = {0,0,0,0};
        #pragma unroll 4
        for (int kt=0; kt<4; kt++){
          f16x8 a = *(const f16x8*)(Xfrag + kt*512 + lane*8);
          f16x8 b = *(const f16x8*)(wb + kt*512 + lane*8);
          a4 = __builtin_amdgcn_mfma_f32_16x16x32_f16(a, b, a4, 0,0,0);
        }
        #pragma unroll 4
        for (int kt=4; kt<20; kt++){
          f16x8 a = *(const f16x8*)(Afrag + (kt-4)*512 + lane*8);
          f16x8 b = *(const f16x8*)(wb + kt*512 + lane*8);
          a4 = __builtin_amdgcn_mfma_f32_16x16x32_f16(a, b, a4, 0,0,0);
        }
        float* o = outb + (w*4+i)*256 + ((lane>>4)*4)*16 + (lane&15);
        o[0]=a4[0]; o[16]=a4[1]; o[32]=a4[2]; o[48]=a4[3];
      }
      __syncthreads();
      {
        const float* o = outb + (16+(q4>>2))*256 + row*16 + (q4&3)*4;
        HU u;
        u.h[0]=__float2half(fmaxf(o[0]+vbp1[0],0.f));
        u.h[1]=__float2half(fmaxf(o[1]+vbp1[1],0.f));
        u.h[2]=__float2half(fmaxf(o[2]+vbp1[2],0.f));
        u.h[3]=__float2half(fmaxf(o[3]+vbp1[3],0.f));
        ast((u64*)(Tf + (size_t)grow*512 + sc), u.q[0]);
      }
      {
        const float* o = outb + q4*256 + row*16;
        HU u0, u1;
        #pragma unroll
        for (int c=0;c<8;c++){ u0.h[c]=__float2half(o[c]); u1.h[c]=__float2half(o[8+c]); }
        u64* d = (u64*)(Gp + (size_t)grow*2048 + (s*16+q4)*16);
        ast(d, u0.q[0]); ast(d+1, u0.q[1]); ast(d+2, u1.q[0]); ast(d+3, u1.q[1]);
      }
      gsync(ctr, 8*(++round));
    }

    // ================= phase 6: P2 + loss + LSTM update =================
    {
      {
        const int ar = t & 15, ch = t >> 4;
        const u64* sp = (const u64*)(Tf + ((size_t)(g*16+ar))*512 + ch*32);
        u64 v[8];
        #pragma unroll
        for (int i=0;i<8;i++) v[i] = ald(sp+i);
        #pragma unroll
        for (int kg=0;kg<4;kg++){
          u64* d = (u64*)(Afrag + ch*512 + (ar + 16*kg)*8);
          d[0] = v[2*kg]; d[1] = v[2*kg+1];
        }
      }
      {
        const int gr = t >> 4, gate = (t&15) >> 2, c16 = (t&3)*16;
        const u64* gp = (const u64*)(Gp + ((size_t)(g*16+gr))*2048 + gate*512 + s*64 + c16);
        u64 a0=ald(gp), a1=ald(gp+1), a2=ald(gp+2), a3=ald(gp+3);
        u64* d = (u64*)(gstage + gr*256 + gate*64 + c16);
        d[0]=a0; d[1]=a1; d[2]=a2; d[3]=a3;
      }
      __syncthreads();
      {
        const __half* wb = Wp2F + (size_t)s*16*512;
        f32x4 a4 = {0,0,0,0};
        #pragma unroll
        for (int kt2=0; kt2<4; kt2++){
          const int kt = w*4 + kt2;
          f16x8 a = *(const f16x8*)(Afrag + kt*512 + lane*8);
          f16x8 b = *(const f16x8*)(wb + kt*512 + lane*8);
          a4 = __builtin_amdgcn_mfma_f32_16x16x32_f16(a, b, a4, 0,0,0);
        }
        float* o = outb + w*256 + ((lane>>4)*4)*16 + (lane&15);
        o[0]=a4[0]; o[16]=a4[1]; o[32]=a4[2]; o[48]=a4[3];
      }
      if (epos >= 0){
        H4 ui,uf,uo,uc;
        ui.q = *(const u64*)(gstage + row*256 +   0 + q4*4);
        uf.q = *(const u64*)(gstage + row*256 +  64 + q4*4);
        uo.q = *(const u64*)(gstage + row*256 + 128 + q4*4);
        uc.q = *(const u64*)(gstage + row*256 + 192 + q4*4);
        HU hu;
        #pragma unroll
        for (int i=0;i<4;i++){
          float ig = sigm(__half2float(ui.h[i]) + vbi[i]);
          float fg = sigm(__half2float(uf.h[i]) + vbf[i]);
          float og = sigm(__half2float(uo.h[i]) + vbo[i]);
          float ct = tanhf(__half2float(uc.h[i]) + vbc[i]);
          Creg[i] = fg*Creg[i] + ig*ct;
          Hreg[i] = og*tanhf(Creg[i]);
          hu.h[i] = __float2half(Hreg[i]);
        }
        ast((u64*)(Hf + (size_t)grow*512 + sc), hu.q[0]);
      }
      __syncthreads();
      if (epos >= 0){
        float p = outb[row*16+q4] + outb[256+row*16+q4]
                + outb[512+row*16+q4] + outb[768+row*16+q4] + vbp2;
        const int d = s*16 + q4;
        float xo = X[((size_t)(k*En+epos))*Dn + d];
        float mo = Mm[((size_t)(k*En+epos))*Dn + d];
        loss_loc += fabsf(xo - p)*mo;
        m_loc    += mo;
      }
      gsync(ctr, 8*(++round));
    }
  }

  // block reduction -> global atomics
  #pragma unroll
  for (int off=32; off>0; off>>=1){
    loss_loc += __shfl_down(loss_loc, off);
    m_loc    += __shfl_down(m_loc, off);
  }
  if (lane == 0){ redbuf[w] = loss_loc; redbuf[4+w] = m_loc; }
  __syncthreads();
  if (t == 0){
    atomicAdd(acc+0, redbuf[0]+redbuf[1]+redbuf[2]+redbuf[3]);
    atomicAdd(acc+1, redbuf[4]+redbuf[5]+redbuf[6]+redbuf[7]);
  }
}

__global__ void k_fin(const float* __restrict__ acc, float* __restrict__ out){
  if (threadIdx.x == 0){
    out[0] = acc[0];
    out[1] = acc[0]/acc[1];
  }
}

extern "C" void kernel_launch(void* const* d_in, const int* in_sizes, int n_in,
                              void* d_out, int out_size, void* d_ws, size_t ws_size,
                              hipStream_t stream)
{
  const float* X   = (const float*)d_in[0];
  const float* Mm  = (const float*)d_in[1];
  const int*  bidx = (const int*)d_in[2];
  const float* Wi  = (const float*)d_in[4];
  const float* bi  = (const float*)d_in[5];
  const float* Wf  = (const float*)d_in[6];
  const float* bff = (const float*)d_in[7];
  const float* Wo  = (const float*)d_in[8];
  const float* bo  = (const float*)d_in[9];
  const float* Wc  = (const float*)d_in[10];
  const float* bc  = (const float*)d_in[11];
  const float* W1  = (const float*)d_in[12];
  const float* b1  = (const float*)d_in[13];
  const float* W2  = (const float*)d_in[14];
  const float* b2  = (const float*)d_in[15];
  const float* Wp1 = (const float*)d_in[16];
  const float* bp1 = (const float*)d_in[17];
  const float* Wp2 = (const float*)d_in[18];
  const float* bp2 = (const float*)d_in[19];

  char* ws = (char*)d_ws;
  int*    pos = (int*)ws;
  float*  acc = (float*)(ws + 131072);
  int*    ctr = (int*)(ws + 131200);
  __half* Hf  = (__half*)(ws + 1048576);
  __half* Tf  = (__half*)(ws + 1572864);
  __half* Gp  = (__half*)(ws + 2097152);
  __half* WF  = (__half*)(ws + 4194304);

  k_init   <<<512, 256, 0, stream>>>(pos, acc, ctr, (uint32_t*)Hf);
  k_scatter<<<(Kn*En + 255)/256, 256, 0, stream>>>(bidx, pos);

  k_cvt_frag<<<(262144+255)/256, 256, 0, stream>>>(W1,  WF,          16, 512, 262144);
  k_cvt_frag<<<(262144+255)/256, 256, 0, stream>>>(W2,  WF + 262144, 16, 512, 262144);
  k_cvt_frag<<<(262144+255)/256, 256, 0, stream>>>(Wp1, WF + 524288, 16, 512, 262144);
  k_cvt_frag<<<(65536 +255)/256, 256, 0, stream>>>(Wp2, WF + 786432, 16, 128, 65536);
  k_cvt_frag<<<(327680+255)/256, 256, 0, stream>>>(Wi,  WF + 851968,            20, 512, 327680);
  k_cvt_frag<<<(327680+255)/256, 256, 0, stream>>>(Wf,  WF + 851968 + 327680,   20, 512, 327680);
  k_cvt_frag<<<(327680+255)/256, 256, 0, stream>>>(Wo,  WF + 851968 + 655360,   20, 512, 327680);
  k_cvt_frag<<<(327680+255)/256, 256, 0, stream>>>(Wc,  WF + 851968 + 983040,   20, 512, 327680);

  k_main<<<NBLK, NTH, 0, stream>>>(X, Mm, pos, WF, Hf, Tf, Gp,
                                   bi, bff, bo, bc, b1, b2, bp1, bp2, acc, ctr);
  k_fin<<<1, 64, 0, stream>>>(acc, (float*)d_out);
}

// Round 7
// 1916.377 us; speedup vs baseline: 4.2665x; 1.1030x over previous
//
#include <hip/hip_runtime.h>
#include <hip/hip_fp16.h>
#include <stdint.h>

#define Kn 64
#define En 256
#define Bn 512
#define Hn 512
#define Dn 128
#define NBLK 256
#define NTH  256
#define DT_C 0.05f

// ws layout (bytes):
//   0        pos   int[Kn*Bn]           (128 KB)
//   131072   acc   float[2]
//   131200   ctr   int, 32 groups x 128B stride (4 KB)
//   1048576  Hf16  __half[512][512]     (512 KB)
//   1572864  Tf16  __half[512][512]     (512 KB)
//   4194304  WF    frag-swizzled f16 weights (4.33 MB)
// WF half-offsets: W1 0, W2 262144, Wp1 524288, Wp2 786432, Wg 851968
//   frag layout per matrix: idx = ((coltile*KT + ktile)*64 + lane)*8 + e
//   element = W[ktile*32 + (lane>>4)*8 + e][coltile*16 + (lane&15)]

typedef _Float16 f16x8 __attribute__((ext_vector_type(8)));
typedef float    f32x4 __attribute__((ext_vector_type(4)));
typedef unsigned long long u64;

__device__ __forceinline__ float sigm(float x){ return 1.0f/(1.0f + __expf(-x)); }

__device__ __forceinline__ u64 ald(const u64* p){
  return __hip_atomic_load(p, __ATOMIC_RELAXED, __HIP_MEMORY_SCOPE_AGENT);
}
__device__ __forceinline__ void ast(u64* p, u64 v){
  __hip_atomic_store(p, v, __ATOMIC_RELAXED, __HIP_MEMORY_SCOPE_AGENT);
}

union HU { __half h[8]; u64 q[2]; uint32_t w[4]; };

__global__ void k_init(int* __restrict__ pos, float* __restrict__ acc,
                       int* __restrict__ ctr, uint32_t* __restrict__ hf){
  int i = blockIdx.x*blockDim.x + threadIdx.x;
  if (i < Kn*Bn) pos[i] = -1;
  if (i < 2) acc[i] = 0.0f;
  if (i < 1024) ctr[i] = 0;
  if (i < Hn*Hn/2) hf[i] = 0;
}

__global__ void k_scatter(const int* __restrict__ bidx, int* __restrict__ pos){
  int i = blockIdx.x*blockDim.x + threadIdx.x;
  if (i < Kn*En){
    int k = i >> 8;
    int e = i & (En-1);
    pos[(k << 9) | bidx[i]] = e;
  }
}

// frag-swizzle convert: dst layout documented above. N = src col count.
__global__ void k_cvt_frag(const float* __restrict__ src, __half* __restrict__ dst,
                           int KT, int N, int n){
  int i = blockIdx.x*blockDim.x + threadIdx.x;
  if (i >= n) return;
  int C = i / (KT*512);
  int r = i % (KT*512);
  int T = r >> 9;
  int q = r & 511;
  int l = q >> 3, e = q & 7;
  int srow = T*32 + ((l>>4)<<3) + e;
  int scol = C*16 + (l&15);
  dst[i] = __float2half(src[(size_t)srow*N + scol]);
}

// 8-block group barrier, fence-free (acq/rel would wipe L2).
// vmcnt(0) drains this block's coherent (sc0/sc1) data stores to the
// coherence point before the flag-add; consumers' coherent loads are
// point-ordered after flag observation. Thread-0-only spin (cheap on L3).
// All 256 blocks co-resident (grid = 256 CUs).
__device__ __forceinline__ void gsync(int* c, int tgt){
  asm volatile("s_waitcnt vmcnt(0)" ::: "memory");
  __syncthreads();
  if (threadIdx.x == 0){
    __hip_atomic_fetch_add(c, 1, __ATOMIC_RELAXED, __HIP_MEMORY_SCOPE_AGENT);
    while (__hip_atomic_load(c, __ATOMIC_RELAXED, __HIP_MEMORY_SCOPE_AGENT) < tgt)
      __builtin_amdgcn_s_sleep(1);
  }
  __syncthreads();
}

__global__ __launch_bounds__(NTH, 1) void k_main(
  const float* __restrict__ X, const float* __restrict__ Mm,
  const int* __restrict__ pos, const __half* __restrict__ WF,
  __half* __restrict__ Hf, __half* __restrict__ Tf,
  const float* __restrict__ bi_, const float* __restrict__ bf_,
  const float* __restrict__ bo_, const float* __restrict__ bc_,
  const float* __restrict__ b1_, const float* __restrict__ b2_,
  const float* __restrict__ bp1_, const float* __restrict__ bp2_,
  float* __restrict__ acc, int* __restrict__ ctrbase)
{
  const __half* W1F  = WF;
  const __half* W2F  = WF + 262144;
  const __half* Wp1F = WF + 524288;
  const __half* Wp2F = WF + 786432;
  const __half* WgF  = WF + 851968;

  const int t    = threadIdx.x;
  const int bid  = blockIdx.x;
  const int s    = bid & 7;      // slice = XCD (round-robin dispatch; perf-only)
  const int g    = bid >> 3;     // group 0..31 (8 blocks, one per XCD)
  const int w    = t >> 6;       // wave 0..3
  const int lane = t & 63;

  int* ctr = ctrbase + g*32;

  __shared__ __align__(16) __half Afrag[16*512];     // 16KB
  __shared__ __align__(16) __half Xfrag[4*512];      // 4KB
  __shared__ __align__(16) float  outb[20*256];      // 20KB
  __shared__ float redbuf[8];

  const int row = t >> 4;
  const int q4  = t & 15;
  const int sc  = s*64 + q4*4;
  float Hreg[4] = {0,0,0,0};
  float Creg[4] = {0,0,0,0};
  float vb1[4], vb2[4], vbp1[4], vbi[4], vbf[4], vbo[4], vbc[4];
  #pragma unroll
  for (int i=0;i<4;i++){
    vb1[i]=b1_[sc+i]; vb2[i]=b2_[sc+i]; vbp1[i]=bp1_[sc+i];
    vbi[i]=bi_[sc+i]; vbf[i]=bf_[sc+i]; vbo[i]=bo_[sc+i]; vbc[i]=bc_[sc+i];
  }
  const float vbp2 = bp2_[s*16 + q4];

  // hoist W1/W2/Wp1 wave-slices into registers (192 VGPRs; 1 wave/SIMD budget 512)
  f16x8 W1r[16], W2r[16], Wp1r[16];
  {
    const size_t cb = (size_t)(s*4 + w)*16*512 + lane*8;
    #pragma unroll
    for (int kt=0; kt<16; kt++){
      W1r[kt]  = *(const f16x8*)(W1F  + cb + kt*512);
      W2r[kt]  = *(const f16x8*)(W2F  + cb + kt*512);
      Wp1r[kt] = *(const f16x8*)(Wp1F + cb + kt*512);
    }
  }

  float loss_loc = 0.f, m_loc = 0.f;
  int round = 0;
  const int grow = g*16 + row;

  for (int k=0; k<Kn; k++){
    const int epos = pos[(k<<9) + grow];

    // ================= 4 Euler phases (reg-resident weights) =================
    #pragma unroll 1
    for (int ph=0; ph<4; ph++){
      const __half* src = (ph & 1) ? Tf : Hf;
      {
        const int ar = t & 15, ch = t >> 4;
        const u64* sp = (const u64*)(src + ((size_t)(g*16+ar))*512 + ch*32);
        u64 v[8];
        #pragma unroll
        for (int i=0;i<8;i++) v[i] = ald(sp+i);
        #pragma unroll
        for (int kg=0;kg<4;kg++){
          u64* d = (u64*)(Afrag + ch*512 + (ar + 16*kg)*8);
          d[0] = v[2*kg]; d[1] = v[2*kg+1];
        }
      }
      __syncthreads();
      {
        f32x4 a4 = {0,0,0,0};
        if (!(ph & 1)){
          #pragma unroll
          for (int kt=0; kt<16; kt++){
            f16x8 a = *(const f16x8*)(Afrag + kt*512 + lane*8);
            a4 = __builtin_amdgcn_mfma_f32_16x16x32_f16(a, W1r[kt], a4, 0,0,0);
          }
        } else {
          #pragma unroll
          for (int kt=0; kt<16; kt++){
            f16x8 a = *(const f16x8*)(Afrag + kt*512 + lane*8);
            a4 = __builtin_amdgcn_mfma_f32_16x16x32_f16(a, W2r[kt], a4, 0,0,0);
          }
        }
        float* o = outb + w*256 + ((lane>>4)*4)*16 + (lane&15);
        o[0]=a4[0]; o[16]=a4[1]; o[32]=a4[2]; o[48]=a4[3];
      }
      __syncthreads();
      {
        const float* o = outb + (q4>>2)*256 + row*16 + (q4&3)*4;
        float v0=o[0], v1=o[1], v2=o[2], v3=o[3];
        HU u;
        if (!(ph & 1)){
          u.h[0]=__float2half(tanhf(v0+vb1[0])); u.h[1]=__float2half(tanhf(v1+vb1[1]));
          u.h[2]=__float2half(tanhf(v2+vb1[2])); u.h[3]=__float2half(tanhf(v3+vb1[3]));
          ast((u64*)(Tf + (size_t)grow*512 + sc), u.q[0]);
        } else {
          Hreg[0] += DT_C*(v0+vb2[0]); Hreg[1] += DT_C*(v1+vb2[1]);
          Hreg[2] += DT_C*(v2+vb2[2]); Hreg[3] += DT_C*(v3+vb2[3]);
          u.h[0]=__float2half(Hreg[0]); u.h[1]=__float2half(Hreg[1]);
          u.h[2]=__float2half(Hreg[2]); u.h[3]=__float2half(Hreg[3]);
          ast((u64*)(Hf + (size_t)grow*512 + sc), u.q[0]);
        }
      }
      gsync(ctr, 8*(++round));
    }

    // ====== phase 5: P1 (reg weights) + gate dots (block-local output) ======
    {
      {
        const int ar = t & 15, ch = t >> 4;
        const u64* sp = (const u64*)(Hf + ((size_t)(g*16+ar))*512 + ch*32);
        u64 v[8];
        #pragma unroll
        for (int i=0;i<8;i++) v[i] = ald(sp+i);
        #pragma unroll
        for (int kg=0;kg<4;kg++){
          u64* d = (u64*)(Afrag + ch*512 + (ar + 16*kg)*8);
          d[0] = v[2*kg]; d[1] = v[2*kg+1];
        }
      }
      if (t < 64){
        const int ar = t & 15, ch = t >> 4;
        const int e = pos[(k<<9) + g*16 + ar];
        float xv[32];
        if (e >= 0){
          const float4* xp = (const float4*)(X + ((size_t)(k*En+e))*Dn + ch*32);
          #pragma unroll
          for (int i=0;i<8;i++){
            float4 f = xp[i];
            xv[4*i]=f.x; xv[4*i+1]=f.y; xv[4*i+2]=f.z; xv[4*i+3]=f.w;
          }
        } else {
          #pragma unroll
          for (int i=0;i<32;i++) xv[i]=0.f;
        }
        #pragma unroll
        for (int kg=0;kg<4;kg++){
          HU u;
          #pragma unroll
          for (int e8=0;e8<8;e8++) u.h[e8] = __float2half(xv[kg*8+e8]);
          u64* d = (u64*)(Xfrag + ch*512 + (ar + 16*kg)*8);
          d[0] = u.q[0]; d[1] = u.q[1];
        }
      }
      __syncthreads();
      // P1 -> slot 16+w
      {
        f32x4 a4 = {0,0,0,0};
        #pragma unroll
        for (int kt=0; kt<16; kt++){
          f16x8 a = *(const f16x8*)(Afrag + kt*512 + lane*8);
          a4 = __builtin_amdgcn_mfma_f32_16x16x32_f16(a, Wp1r[kt], a4, 0,0,0);
        }
        float* o = outb + (16+w)*256 + ((lane>>4)*4)*16 + (lane&15);
        o[0]=a4[0]; o[16]=a4[1]; o[32]=a4[2]; o[48]=a4[3];
      }
      // gates: wave w = gate w; subtiles i cover exactly our slice's columns.
      // Cg = w*32 + s*4 + i  -> preact cols (gate w, h-cols s*64+i*16..+15)
      #pragma unroll 1
      for (int i=0;i<4;i++){
        const int Cg = w*32 + s*4 + i;
        const __half* wb = WgF + (size_t)Cg*20*512;
        f32x4 a4 = {0,0,0,0};
        #pragma unroll 4
        for (int kt=0; kt<4; kt++){
          f16x8 a = *(const f16x8*)(Xfrag + kt*512 + lane*8);
          f16x8 b = *(const f16x8*)(wb + kt*512 + lane*8);
          a4 = __builtin_amdgcn_mfma_f32_16x16x32_f16(a, b, a4, 0,0,0);
        }
        #pragma unroll 4
        for (int kt=4; kt<20; kt++){
          f16x8 a = *(const f16x8*)(Afrag + (kt-4)*512 + lane*8);
          f16x8 b = *(const f16x8*)(wb + kt*512 + lane*8);
          a4 = __builtin_amdgcn_mfma_f32_16x16x32_f16(a, b, a4, 0,0,0);
        }
        float* o = outb + (w*4+i)*256 + ((lane>>4)*4)*16 + (lane&15);
        o[0]=a4[0]; o[16]=a4[1]; o[32]=a4[2]; o[48]=a4[3];
      }
      __syncthreads();
      // store T slice (P1 relu); gate preacts persist in outb[0..15] across gsync
      {
        const float* o = outb + (16+(q4>>2))*256 + row*16 + (q4&3)*4;
        HU u;
        u.h[0]=__float2half(fmaxf(o[0]+vbp1[0],0.f));
        u.h[1]=__float2half(fmaxf(o[1]+vbp1[1],0.f));
        u.h[2]=__float2half(fmaxf(o[2]+vbp1[2],0.f));
        u.h[3]=__float2half(fmaxf(o[3]+vbp1[3],0.f));
        ast((u64*)(Tf + (size_t)grow*512 + sc), u.q[0]);
      }
      gsync(ctr, 8*(++round));
    }

    // ============ phase 6: P2 + loss + LSTM update (gates from LDS) ============
    {
      {
        const int ar = t & 15, ch = t >> 4;
        const u64* sp = (const u64*)(Tf + ((size_t)(g*16+ar))*512 + ch*32);
        u64 v[8];
        #pragma unroll
        for (int i=0;i<8;i++) v[i] = ald(sp+i);
        #pragma unroll
        for (int kg=0;kg<4;kg++){
          u64* d = (u64*)(Afrag + ch*512 + (ar + 16*kg)*8);
          d[0] = v[2*kg]; d[1] = v[2*kg+1];
        }
      }
      __syncthreads();
      // P2: coltile s of Wp2, wave w does ktiles w*4..+3 -> slot 16+w
      {
        const __half* wb = Wp2F + (size_t)s*16*512;
        f32x4 a4 = {0,0,0,0};
        #pragma unroll
        for (int kt2=0; kt2<4; kt2++){
          const int kt = w*4 + kt2;
          f16x8 a = *(const f16x8*)(Afrag + kt*512 + lane*8);
          f16x8 b = *(const f16x8*)(wb + kt*512 + lane*8);
          a4 = __builtin_amdgcn_mfma_f32_16x16x32_f16(a, b, a4, 0,0,0);
        }
        float* o = outb + (16+w)*256 + ((lane>>4)*4)*16 + (lane&15);
        o[0]=a4[0]; o[16]=a4[1]; o[32]=a4[2]; o[48]=a4[3];
      }
      // LSTM update from outb gate slots (written phase 5, disjoint from P2 slots)
      if (epos >= 0){
        const int sub = q4 >> 2, off = row*16 + (q4&3)*4;
        const float4 pi = *(const float4*)(outb + (0*4+sub)*256 + off);
        const float4 pf = *(const float4*)(outb + (1*4+sub)*256 + off);
        const float4 po = *(const float4*)(outb + (2*4+sub)*256 + off);
        const float4 pc = *(const float4*)(outb + (3*4+sub)*256 + off);
        HU hu;
        const float gi[4]={pi.x,pi.y,pi.z,pi.w}, gf[4]={pf.x,pf.y,pf.z,pf.w};
        const float go[4]={po.x,po.y,po.z,po.w}, gc[4]={pc.x,pc.y,pc.z,pc.w};
        #pragma unroll
        for (int i=0;i<4;i++){
          float ig = sigm(gi[i] + vbi[i]);
          float fg = sigm(gf[i] + vbf[i]);
          float og = sigm(go[i] + vbo[i]);
          float ct = tanhf(gc[i] + vbc[i]);
          Creg[i] = fg*Creg[i] + ig*ct;
          Hreg[i] = og*tanhf(Creg[i]);
          hu.h[i] = __float2half(Hreg[i]);
        }
        ast((u64*)(Hf + (size_t)grow*512 + sc), hu.q[0]);
      }
      __syncthreads();
      if (epos >= 0){
        float p = outb[16*256 + row*16+q4] + outb[17*256 + row*16+q4]
                + outb[18*256 + row*16+q4] + outb[19*256 + row*16+q4] + vbp2;
        const int d = s*16 + q4;
        float xo = X[((size_t)(k*En+epos))*Dn + d];
        float mo = Mm[((size_t)(k*En+epos))*Dn + d];
        loss_loc += fabsf(xo - p)*mo;
        m_loc    += mo;
      }
      gsync(ctr, 8*(++round));
    }
  }

  // block reduction -> global atomics
  #pragma unroll
  for (int off=32; off>0; off>>=1){
    loss_loc += __shfl_down(loss_loc, off);
    m_loc    += __shfl_down(m_loc, off);
  }
  if (lane == 0){ redbuf[w] = loss_loc; redbuf[4+w] = m_loc; }
  __syncthreads();
  if (t == 0){
    atomicAdd(acc+0, redbuf[0]+redbuf[1]+redbuf[2]+redbuf[3]);
    atomicAdd(acc+1, redbuf[4]+redbuf[5]+redbuf[6]+redbuf[7]);
  }
}

__global__ void k_fin(const float* __restrict__ acc, float* __restrict__ out){
  if (threadIdx.x == 0){
    out[0] = acc[0];
    out[1] = acc[0]/acc[1];
  }
}

extern "C" void kernel_launch(void* const* d_in, const int* in_sizes, int n_in,
                              void* d_out, int out_size, void* d_ws, size_t ws_size,
                              hipStream_t stream)
{
  const float* X   = (const float*)d_in[0];
  const float* Mm  = (const float*)d_in[1];
  const int*  bidx = (const int*)d_in[2];
  const float* Wi  = (const float*)d_in[4];
  const float* bi  = (const float*)d_in[5];
  const float* Wf  = (const float*)d_in[6];
  const float* bff = (const float*)d_in[7];
  const float* Wo  = (const float*)d_in[8];
  const float* bo  = (const float*)d_in[9];
  const float* Wc  = (const float*)d_in[10];
  const float* bc  = (const float*)d_in[11];
  const float* W1  = (const float*)d_in[12];
  const float* b1  = (const float*)d_in[13];
  const float* W2  = (const float*)d_in[14];
  const float* b2  = (const float*)d_in[15];
  const float* Wp1 = (const float*)d_in[16];
  const float* bp1 = (const float*)d_in[17];
  const float* Wp2 = (const float*)d_in[18];
  const float* bp2 = (const float*)d_in[19];

  char* ws = (char*)d_ws;
  int*    pos = (int*)ws;
  float*  acc = (float*)(ws + 131072);
  int*    ctr = (int*)(ws + 131200);
  __half* Hf  = (__half*)(ws + 1048576);
  __half* Tf  = (__half*)(ws + 1572864);
  __half* WF  = (__half*)(ws + 4194304);

  k_init   <<<512, 256, 0, stream>>>(pos, acc, ctr, (uint32_t*)Hf);
  k_scatter<<<(Kn*En + 255)/256, 256, 0, stream>>>(bidx, pos);

  k_cvt_frag<<<(262144+255)/256, 256, 0, stream>>>(W1,  WF,          16, 512, 262144);
  k_cvt_frag<<<(262144+255)/256, 256, 0, stream>>>(W2,  WF + 262144, 16, 512, 262144);
  k_cvt_frag<<<(262144+255)/256, 256, 0, stream>>>(Wp1, WF + 524288, 16, 512, 262144);
  k_cvt_frag<<<(65536 +255)/256, 256, 0, stream>>>(Wp2, WF + 786432, 16, 128, 65536);
  k_cvt_frag<<<(327680+255)/256, 256, 0, stream>>>(Wi,  WF + 851968,            20, 512, 327680);
  k_cvt_frag<<<(327680+255)/256, 256, 0, stream>>>(Wf,  WF + 851968 + 327680,   20, 512, 327680);
  k_cvt_frag<<<(327680+255)/256, 256, 0, stream>>>(Wo,  WF + 851968 + 655360,   20, 512, 327680);
  k_cvt_frag<<<(327680+255)/256, 256, 0, stream>>>(Wc,  WF + 851968 + 983040,   20, 512, 327680);

  k_main<<<NBLK, NTH, 0, stream>>>(X, Mm, pos, WF, Hf, Tf,
                                   bi, bff, bo, bc, b1, b2, bp1, bp2, acc, ctr);
  k_fin<<<1, 64, 0, stream>>>(acc, (float*)d_out);
}